// Round 4
// baseline (224.399 us; speedup 1.0000x reference)
//
#include <hip/hip_runtime.h>
#include <math.h>

#define Bd 2
#define Sd 2048
#define Ed 1024
#define Hd 16
#define Dd 64
#define Md (Bd * Sd)     // 4096
#define Kd 1024          // GEMM K == E
#define Nd 1024          // GEMM N == E

typedef __attribute__((ext_vector_type(8))) short bf16x8;
typedef __attribute__((ext_vector_type(4))) float f32x4;

__device__ __forceinline__ unsigned short f2bf(float f) {   // RNE (epilogues)
    unsigned x = __float_as_uint(f);
    x += 0x7fffu + ((x >> 16) & 1u);
    return (unsigned short)(x >> 16);
}

// round-half-up bf16 pack of two floats -> one dword via v_perm_b32
__device__ __forceinline__ unsigned pk_bf16_rhu(float a, float b) {
    return __builtin_amdgcn_perm(__float_as_uint(b) + 0x8000u,
                                 __float_as_uint(a) + 0x8000u, 0x07060302u);
}

__device__ __forceinline__ void gl2lds16(const unsigned short* g, unsigned short* l) {
    // 16B-per-lane async global->LDS (global_load_lds_dwordx4).
    __builtin_amdgcn_global_load_lds(
        (__attribute__((address_space(1))) void*)g,
        (__attribute__((address_space(3))) void*)l, 16, 0, 0);
}

// ---------------------------------------------------------------------------
// Prep kernel: fused cvt3 (q/k/v fp32->bf16) + wtrans (4x weight T+cvt).
// NOTE (r8, r13): fusing the q/k/v cvt into the proj K-loop fails at any
// register-pipeline depth — keep it as a separate bandwidth-bound pass.
// ---------------------------------------------------------------------------
__global__ __launch_bounds__(256) void prep_k(
    const float* __restrict__ q, const float* __restrict__ k, const float* __restrict__ v,
    unsigned short* __restrict__ qb, unsigned short* __restrict__ kb,
    unsigned short* __restrict__ vb,
    const float* __restrict__ w0, const float* __restrict__ w1,
    const float* __restrict__ w2, const float* __restrict__ w3,
    unsigned short* __restrict__ o0, unsigned short* __restrict__ o1,
    unsigned short* __restrict__ o2, unsigned short* __restrict__ o3)
{
    const int bx = blockIdx.x;
    if (bx < 3072) {
        const int zz = bx >> 10;            // tensor 0..2
        const int blk = bx & 1023;
        const float* s = zz == 0 ? q : zz == 1 ? k : v;
        unsigned short* d = zz == 0 ? qb : zz == 1 ? kb : vb;
        const int n4 = (Bd * Sd * Ed) / 4;  // float4 count
        int i = blk * 256 + threadIdx.x;
        for (; i < n4; i += 1024 * 256) {
            float4 x = ((const float4*)s)[i];
            uint2 u = make_uint2(pk_bf16_rhu(x.x, x.y), pk_bf16_rhu(x.z, x.w));
            ((uint2*)d)[i] = u;
        }
        return;
    }
    __shared__ unsigned short Tl[32][36];
    const int idx = bx - 3072;              // 0..4095
    const int z   = idx >> 10;              // weight 0..3
    const int ky  = (idx >> 5) & 31;
    const int nx  = idx & 31;
    const float* W = z == 0 ? w0 : z == 1 ? w1 : z == 2 ? w2 : w3;
    unsigned short* Wt = z == 0 ? o0 : z == 1 ? o1 : z == 2 ? o2 : o3;

    const int t = threadIdx.x;
    const int r = t >> 3;
    const int c4 = (t & 7) * 4;
    const int k0 = ky * 32;
    const int n0 = nx * 32;

    float4 x = *(const float4*)(W + (size_t)(k0 + r) * Nd + n0 + c4);
    Tl[c4 + 0][r] = f2bf(x.x);
    Tl[c4 + 1][r] = f2bf(x.y);
    Tl[c4 + 2][r] = f2bf(x.z);
    Tl[c4 + 3][r] = f2bf(x.w);
    __syncthreads();
    ushort4 u = make_ushort4(Tl[r][c4 + 0], Tl[r][c4 + 1], Tl[r][c4 + 2], Tl[r][c4 + 3]);
    *(ushort4*)(Wt + (size_t)(n0 + r) * Kd + k0 + c4) = u;
}

// ---------------------------------------------------------------------------
// bf16 MFMA GEMM: C = A @ Bt^T (+bias)*oscale.  AMx128 tile (AM=128|64),
// BK=32, double-buffered LDS, ONE barrier per K-iter; staging via
// global_load_lds width-16 (full-iteration async depth).
// mode 0: fp32 flat [M,N];  mode 1: bf16 [B,H,S,D];  mode 2: bf16 [B,H,D,S]
// ---------------------------------------------------------------------------
template <int AM>
__device__ __forceinline__ void gemm_v5(
    const unsigned short* __restrict__ A, const unsigned short* __restrict__ Bt,
    const float* __restrict__ bias, void* __restrict__ Yv,
    int m0, int n0, int mode, float oscale)
{
    constexpr int AMT = AM / 32;               // per-wave m mfma tiles (4|2)
    __shared__ unsigned short As[2][AM * 32];
    __shared__ unsigned short Bs[2][128 * 32];

    const int tid  = threadIdx.x;
    const int w    = tid >> 6;
    const int lane = tid & 63;
    const int ln   = lane & 15;
    const int quad = lane >> 4;
    const int wm = (w >> 1) * (AM / 2);
    const int wn = (w & 1) * 64;

    const int lrow = lane >> 2;        // 0..15
    const int lcol = (lane & 3) * 8;   // element offset (8 bf16 per lane)

    const unsigned short* Bg0 = Bt + (size_t)(n0 + (2 * w) * 16 + lrow) * Kd + lcol;
    const unsigned short* Bg1 = Bg0 + 16 * Kd;
    const int aseg = (AM == 128) ? 2 * w : w;
    const unsigned short* Ag0 = A + (size_t)(m0 + aseg * 16 + lrow) * Kd + lcol;
    const unsigned short* Ag1 = Ag0 + 16 * Kd;

    f32x4 acc[AMT][4];
    #pragma unroll
    for (int i = 0; i < AMT; ++i)
        #pragma unroll
        for (int j = 0; j < 4; ++j)
            acc[i][j] = (f32x4){0.f, 0.f, 0.f, 0.f};

    gl2lds16(Bg0, &Bs[0][(2 * w) * 512]);
    gl2lds16(Bg1, &Bs[0][(2 * w) * 512 + 512]);
    gl2lds16(Ag0, &As[0][aseg * 512]);
    if constexpr (AM == 128) gl2lds16(Ag1, &As[0][aseg * 512 + 512]);

    for (int k0 = 0; k0 < Kd; k0 += 32) {
        const int buf = (k0 >> 5) & 1;
        __syncthreads();   // drains staging of buf; reads of buf^1 complete

        if (k0 + 32 < Kd) {   // prefetch next iter into buf^1 (full-iter slack)
            gl2lds16(Bg0 + k0 + 32, &Bs[buf ^ 1][(2 * w) * 512]);
            gl2lds16(Bg1 + k0 + 32, &Bs[buf ^ 1][(2 * w) * 512 + 512]);
            gl2lds16(Ag0 + k0 + 32, &As[buf ^ 1][aseg * 512]);
            if constexpr (AM == 128)
                gl2lds16(Ag1 + k0 + 32, &As[buf ^ 1][aseg * 512 + 512]);
        }

        bf16x8 af[AMT], bfr[4];
        #pragma unroll
        for (int mi = 0; mi < AMT; ++mi)
            af[mi] = *(const bf16x8*)(&As[buf][(wm + mi * 16 + ln) * 32 + quad * 8]);
        #pragma unroll
        for (int ni = 0; ni < 4; ++ni)
            bfr[ni] = *(const bf16x8*)(&Bs[buf][(wn + ni * 16 + ln) * 32 + quad * 8]);
        #pragma unroll
        for (int mi = 0; mi < AMT; ++mi)
            #pragma unroll
            for (int ni = 0; ni < 4; ++ni)
                acc[mi][ni] = __builtin_amdgcn_mfma_f32_16x16x32_bf16(
                    af[mi], bfr[ni], acc[mi][ni], 0, 0, 0);
    }

    float bval[4];
    #pragma unroll
    for (int ni = 0; ni < 4; ++ni) bval[ni] = bias[n0 + wn + ni * 16 + ln];

    if (mode == 0) {
        float* Y = (float*)Yv;
        #pragma unroll
        for (int mi = 0; mi < AMT; ++mi) {
            #pragma unroll
            for (int ni = 0; ni < 4; ++ni) {
                int n = n0 + wn + ni * 16 + ln;
                #pragma unroll
                for (int r = 0; r < 4; ++r) {
                    int m = m0 + wm + mi * 16 + quad * 4 + r;
                    Y[(size_t)m * Nd + n] = (acc[mi][ni][r] + bval[ni]) * oscale;
                }
            }
        }
    } else if (mode == 1) {
        unsigned short* Y = (unsigned short*)Yv;
        #pragma unroll
        for (int mi = 0; mi < AMT; ++mi) {
            #pragma unroll
            for (int ni = 0; ni < 4; ++ni) {
                int n = n0 + wn + ni * 16 + ln;
                int h = n >> 6, d = n & 63;
                #pragma unroll
                for (int r = 0; r < 4; ++r) {
                    int m = m0 + wm + mi * 16 + quad * 4 + r;
                    int b = m >> 11, s = m & 2047;
                    Y[(((size_t)b * Hd + h) * Sd + s) * Dd + d] =
                        f2bf((acc[mi][ni][r] + bval[ni]) * oscale);
                }
            }
        }
    } else {
        unsigned short* Y = (unsigned short*)Yv;
        #pragma unroll
        for (int mi = 0; mi < AMT; ++mi) {
            int mbase = m0 + wm + mi * 16 + quad * 4;
            int b = mbase >> 11, s = mbase & 2047;
            #pragma unroll
            for (int ni = 0; ni < 4; ++ni) {
                int n = n0 + wn + ni * 16 + ln;
                int h = n >> 6, d = n & 63;
                ushort4 u = make_ushort4(
                    f2bf((acc[mi][ni][0] + bval[ni]) * oscale),
                    f2bf((acc[mi][ni][1] + bval[ni]) * oscale),
                    f2bf((acc[mi][ni][2] + bval[ni]) * oscale),
                    f2bf((acc[mi][ni][3] + bval[ni]) * oscale));
                *(ushort4*)(Y + (((size_t)b * Hd + h) * Dd + d) * Sd + s) = u;
            }
        }
    }
}

// Q/K/V projection (bf16 A).  Flat 768-block grid, XCD-aware decode.
__global__ __launch_bounds__(256) void proj_gemm_k(
    const unsigned short* A0, const unsigned short* A1, const unsigned short* A2,
    const unsigned short* B0, const unsigned short* B1, const unsigned short* B2,
    const float* b0, const float* b1, const float* b2,
    unsigned short* Y0, unsigned short* Y1, unsigned short* Y2)
{
    const int l    = blockIdx.x;
    const int xcd  = l & 7;
    const int g    = l >> 3;          // 0..95
    const int n_t  = g & 7;
    const int msub = (g >> 3) & 3;
    const int z    = g >> 5;          // 0..2
    const int m_t  = xcd * 4 + msub;

    const unsigned short* A = z == 0 ? A0 : z == 1 ? A1 : A2;
    const unsigned short* B = z == 0 ? B0 : z == 1 ? B1 : B2;
    const float* bias       = z == 0 ? b0 : z == 1 ? b1 : b2;
    unsigned short* Y       = z == 0 ? Y0 : z == 1 ? Y1 : Y2;
    gemm_v5<128>(A, B, bias, Y, m_t * 128, n_t * 128,
                 z == 2 ? 2 : 1,
                 z == 0 ? 0.18033688011112042f : 1.0f);  // 0.125*log2(e)
}

// Output projection: 64x128 tiles -> 512 blocks (2/CU), XCD swizzle.
__global__ __launch_bounds__(256) void out_gemm_k(
    const unsigned short* A, const unsigned short* Bt, const float* bias, float* Y)
{
    const int l    = blockIdx.x;
    const int xcd  = l & 7;
    const int g    = l >> 3;          // 0..63
    const int n_t  = g & 7;
    const int msub = g >> 3;          // 0..7
    const int m_t  = xcd * 8 + msub;  // 0..63 (64-row tiles)
    gemm_v5<64>(A, Bt, bias, Y, m_t * 64, n_t * 128, 0, 1.0f);
}

// ---------------------------------------------------------------------------
// Flash-style causal attention, r19 (key-split 8-wave):  r18's dual-q body
// and staging machinery, but 512-thread blocks where wave-group 0 (waves
// with w8>>2==0) processes EVEN subtiles and group 1 ODD subtiles of the
// same q-pair.  The no-max raw-exp2 softmax makes O,l pure sums over keys,
// so the key-split merges with one LDS add at the end.  Rationale (r18
// counters): per-SIMD issue ~28% at 2 waves/SIMD -> latency-bound; this
// doubles resident waves (4/SIMD) at the same staging cadence.
//   - LDS packed to EXACTLY 80 KB (one carved array: Ks 32K + Vs 32K +
//     Pt[8][16][64] 16K, XOR-swizzled instead of padded) -> 2 blocks/CU,
//     16 waves/CU.  Do not exceed 81920 bytes.
//   - __launch_bounds__(512,4) pins VGPR<=128 (r18 used 112 - mild cap).
// r16/r17 post-mortem stands: NO direct-global K/V loads (compiler sinks
// them -> serialized L2 latency); all K/V via global_load_lds.
// ---------------------------------------------------------------------------
__global__ __launch_bounds__(512, 4) void attn_mfma_k(
    const unsigned short* __restrict__ Qg,   // [B,H,S,D] bf16, pre-scaled
    const unsigned short* __restrict__ Kg,   // [B,H,S,D] bf16
    const unsigned short* __restrict__ Vg,   // [B,H,D,S] bf16
    unsigned short* __restrict__ Aout)       // [B,S,E] bf16
{
    __shared__ unsigned short lds_all[40960];          // 80 KB exactly
    unsigned short* Ksb = lds_all;                     // [2][2][64*64]
    unsigned short* Vsb = lds_all + 16384;             // [2][2][64*64]
    unsigned short* Ptb = lds_all + 32768;             // [8][16][64] swizzled

    const int tid  = threadIdx.x;
    const int w8   = tid >> 6;          // 0..7
    const int grp  = w8 >> 2;           // 0: even subtiles, 1: odd
    const int w    = w8 & 3;            // q-row slice (16 rows)
    const int lane = tid & 63;
    const int ln   = lane & 15;
    const int quad = lane >> 4;

    const int l   = blockIdx.x;               // 0..511
    const int bh  = (l & 7) * 4 + ((l >> 3) & 3);
    const int qtA = l >> 5;                   // 0..15 (heaviest staging first)
    const int qtB = 31 - qtA;                 // 16..31
    const int b   = bh >> 4;
    const int h   = bh & 15;

    const size_t baseQK = (size_t)bh * Sd * Dd;
    const size_t baseV  = (size_t)bh * Dd * Sd;
    const f32x4 vzero = {0.f, 0.f, 0.f, 0.f};

    const int nsub = qtB + 1;                 // staged subtiles: 17..32
    const int ngrp = (nsub + 1) >> 1;         // barrier groups:   9..16

    // staging: each wave stages 8 rows (rw..rw+7) of each K/V subtile
    const int rw = w8 * 8;
    const int sr = lane >> 3;                 // 0..7
    const int sc = ((lane & 7) ^ sr) * 8;     // XOR-swizzled source col-chunk
    const int swl = ln & 7;
    const int c0 = ((quad    ) ^ swl) * 8;
    const int c1 = ((quad + 4) ^ swl) * 8;
    const int pswz = swl << 3;                // Pt element-XOR swizzle

    const int qrowA = qtA * 64 + w * 16;
    const int qrowB = qtB * 64 + w * 16;
    const int qgA = qrowA + ln, qgB = qrowB + ln;
    const unsigned short* qpA = Qg + baseQK + (size_t)qgA * Dd + 8 * quad;
    const unsigned short* qpB = Qg + baseQK + (size_t)qgB * Dd + 8 * quad;
    const bf16x8 qA0 = *(const bf16x8*)(qpA), qA1 = *(const bf16x8*)(qpA + 32);
    const bf16x8 qB0 = *(const bf16x8*)(qpB), qB1 = *(const bf16x8*)(qpB + 32);

    float lA = 0.f, lB = 0.f;
    f32x4 OA[4], OB[4];
    #pragma unroll
    for (int t = 0; t < 4; ++t) { OA[t] = vzero; OB[t] = vzero; }

    const unsigned short* Kst = Kg + baseQK + (size_t)(rw + sr) * Dd + sc;
    const unsigned short* Vst = Vg + baseV  + (size_t)(rw + sr) * Sd + sc;
    unsigned short* Ptw = Ptb + (w8 * 16 + ln) * 64;

    // prologue: stage subtiles 0,1 into buffer 0 (nsub >= 17, both exist)
    #pragma unroll
    for (int s = 0; s < 2; ++s) {
        const int nk = s * 64;
        gl2lds16(Kst + (size_t)nk * Dd, Ksb + s * 4096 + rw * 64);
        gl2lds16(Vst + nk,              Vsb + s * 4096 + rw * 64);
    }

    for (int g = 0; g < ngrp; ++g) {
        const int cur = g & 1;
        __syncthreads();   // drains staging of buf[cur]; prev reads complete

        // prefetch group g+1 (subtiles 2g+2, 2g+3) into buf[cur^1]
        if (g + 1 < ngrp) {
            #pragma unroll
            for (int s = 0; s < 2; ++s) {
                const int ts = 2 * (g + 1) + s;
                if (ts < nsub) {      // block-uniform
                    const int nk = ts * 64;
                    gl2lds16(Kst + (size_t)nk * Dd,
                             Ksb + ((cur ^ 1) * 2 + s) * 4096 + rw * 64);
                    gl2lds16(Vst + nk,
                             Vsb + ((cur ^ 1) * 2 + s) * 4096 + rw * 64);
                }
            }
        }

        const int it = 2 * g + grp;           // this group's subtile
        if (it < nsub) {
            const int nk  = it * 64;
            const bool doA = (it <= qtA);     // wave-uniform
            const unsigned short* Kc = Ksb + (cur * 2 + grp) * 4096;
            const unsigned short* Vc = Vsb + (cur * 2 + grp) * 4096;

            // K fragments once; feed BOTH q-tiles' QK^T
            bf16x8 kf0[4], kf1[4];
            #pragma unroll
            for (int t = 0; t < 4; ++t) {
                const int R = (t * 16 + ln) * 64;
                kf0[t] = *(const bf16x8*)&Kc[R + c0];
                kf1[t] = *(const bf16x8*)&Kc[R + c1];
            }

            f32x4 SB[4], SA[4];
            #pragma unroll
            for (int t = 0; t < 4; ++t) {
                f32x4 z = __builtin_amdgcn_mfma_f32_16x16x32_bf16(kf0[t], qB0, vzero, 0, 0, 0);
                SB[t]   = __builtin_amdgcn_mfma_f32_16x16x32_bf16(kf1[t], qB1, z,     0, 0, 0);
            }
            if (doA) {
                #pragma unroll
                for (int t = 0; t < 4; ++t) {
                    f32x4 z = __builtin_amdgcn_mfma_f32_16x16x32_bf16(kf0[t], qA0, vzero, 0, 0, 0);
                    SA[t]   = __builtin_amdgcn_mfma_f32_16x16x32_bf16(kf1[t], qA1, z,     0, 0, 0);
                }
            }

            if (it == qtB) {   // diagonal for tile B (last subtile)
                #pragma unroll
                for (int t = 0; t < 4; ++t)
                    #pragma unroll
                    for (int r = 0; r < 4; ++r)
                        if (nk + t * 16 + quad * 4 + r > qgB)
                            SB[t][r] = -1e30f;
            }
            if (doA && it == qtA) {   // diagonal for tile A
                #pragma unroll
                for (int t = 0; t < 4; ++t)
                    #pragma unroll
                    for (int r = 0; r < 4; ++r)
                        if (nk + t * 16 + quad * 4 + r > qgA)
                            SA[t][r] = -1e30f;
            }

            // softmax B -> pfB via wave-private swizzled Pt (no barrier)
            {
                float p[16]; float rsum = 0.f;
                #pragma unroll
                for (int t = 0; t < 4; ++t)
                    #pragma unroll
                    for (int r = 0; r < 4; ++r) {
                        float e = __builtin_amdgcn_exp2f(SB[t][r]);
                        p[t * 4 + r] = e; rsum += e;
                    }
                lB += rsum;
                #pragma unroll
                for (int t = 0; t < 4; ++t) {
                    uint2 u = make_uint2(pk_bf16_rhu(p[t * 4 + 0], p[t * 4 + 1]),
                                         pk_bf16_rhu(p[t * 4 + 2], p[t * 4 + 3]));
                    *(uint2*)&Ptw[(t * 16 + quad * 4) ^ pswz] = u;
                }
            }
            const bf16x8 pfB0 = *(const bf16x8*)&Ptw[(8 * quad) ^ pswz];
            const bf16x8 pfB1 = *(const bf16x8*)&Ptw[(32 + 8 * quad) ^ pswz];

            // softmax A -> pfA (Pt reused after pfB reads; same-wave order)
            bf16x8 pfA0, pfA1;
            if (doA) {
                float p[16]; float rsum = 0.f;
                #pragma unroll
                for (int t = 0; t < 4; ++t)
                    #pragma unroll
                    for (int r = 0; r < 4; ++r) {
                        float e = __builtin_amdgcn_exp2f(SA[t][r]);
                        p[t * 4 + r] = e; rsum += e;
                    }
                lA += rsum;
                #pragma unroll
                for (int t = 0; t < 4; ++t) {
                    uint2 u = make_uint2(pk_bf16_rhu(p[t * 4 + 0], p[t * 4 + 1]),
                                         pk_bf16_rhu(p[t * 4 + 2], p[t * 4 + 3]));
                    *(uint2*)&Ptw[(t * 16 + quad * 4) ^ pswz] = u;
                }
                pfA0 = *(const bf16x8*)&Ptw[(8 * quad) ^ pswz];
                pfA1 = *(const bf16x8*)&Ptw[(32 + 8 * quad) ^ pswz];
            }

            // V fragments once; feed BOTH q-tiles' PV
            #pragma unroll
            for (int t = 0; t < 4; ++t) {
                const int R = (t * 16 + ln) * 64;
                bf16x8 v0 = *(const bf16x8*)&Vc[R + c0];
                bf16x8 v1 = *(const bf16x8*)&Vc[R + c1];
                OB[t] = __builtin_amdgcn_mfma_f32_16x16x32_bf16(v0, pfB0, OB[t], 0, 0, 0);
                OB[t] = __builtin_amdgcn_mfma_f32_16x16x32_bf16(v1, pfB1, OB[t], 0, 0, 0);
                if (doA) {
                    OA[t] = __builtin_amdgcn_mfma_f32_16x16x32_bf16(v0, pfA0, OA[t], 0, 0, 0);
                    OA[t] = __builtin_amdgcn_mfma_f32_16x16x32_bf16(v1, pfA1, OA[t], 0, 0, 0);
                }
            }
        }
    }

    // merge grp1's key-partial O/l into grp0 via LDS (staging is dead now)
    __syncthreads();
    float* mrg = (float*)lds_all;                 // 36 f32 stride, 16B aligned
    const int slot = (w * 64 + lane) * 36;
    if (grp == 1) {
        #pragma unroll
        for (int t = 0; t < 4; ++t) {
            *(f32x4*)&mrg[slot + t * 4]      = OA[t];
            *(f32x4*)&mrg[slot + 16 + t * 4] = OB[t];
        }
        mrg[slot + 32] = lA;
        mrg[slot + 33] = lB;
    }
    __syncthreads();
    if (grp == 0) {
        #pragma unroll
        for (int t = 0; t < 4; ++t) {
            OA[t] += *(const f32x4*)&mrg[slot + t * 4];
            OB[t] += *(const f32x4*)&mrg[slot + 16 + t * 4];
        }
        lA += mrg[slot + 32];
        lB += mrg[slot + 33];

        float lrA = lA;
        lrA += __shfl_xor(lrA, 16);
        lrA += __shfl_xor(lrA, 32);
        float invA = 1.f / lrA;
        unsigned short* opA = Aout + ((size_t)b * Sd + qgA) * Ed + h * 64 + quad * 4;
        #pragma unroll
        for (int t = 0; t < 4; ++t) {
            ushort4 u = make_ushort4(f2bf(OA[t][0] * invA), f2bf(OA[t][1] * invA),
                                     f2bf(OA[t][2] * invA), f2bf(OA[t][3] * invA));
            *(ushort4*)(opA + t * 16) = u;
        }

        float lrB = lB;
        lrB += __shfl_xor(lrB, 16);
        lrB += __shfl_xor(lrB, 32);
        float invB = 1.f / lrB;
        unsigned short* opB = Aout + ((size_t)b * Sd + qgB) * Ed + h * 64 + quad * 4;
        #pragma unroll
        for (int t = 0; t < 4; ++t) {
            ushort4 u = make_ushort4(f2bf(OB[t][0] * invB), f2bf(OB[t][1] * invB),
                                     f2bf(OB[t][2] * invB), f2bf(OB[t][3] * invB));
            *(ushort4*)(opB + t * 16) = u;
        }
    }
}

// ---------------------------------------------------------------------------
extern "C" void kernel_launch(void* const* d_in, const int* in_sizes, int n_in,
                              void* d_out, int out_size, void* d_ws, size_t ws_size,
                              hipStream_t stream) {
    const float* q  = (const float*)d_in[0];
    const float* k  = (const float*)d_in[1];
    const float* v  = (const float*)d_in[2];
    const float* Wq = (const float*)d_in[3];
    const float* bq = (const float*)d_in[4];
    const float* Wk = (const float*)d_in[5];
    const float* bk = (const float*)d_in[6];
    const float* Wv = (const float*)d_in[7];
    const float* bv = (const float*)d_in[8];
    const float* Wo = (const float*)d_in[9];
    const float* bo = (const float*)d_in[10];

    const size_t TENS = (size_t)Bd * Sd * Ed;  // 4,194,304
    const size_t WE   = (size_t)Ed * Ed;       // 1,048,576
    unsigned short* qb  = (unsigned short*)d_ws;   // bf16 [M,K]
    unsigned short* kb  = qb + TENS;
    unsigned short* vb  = kb + TENS;
    unsigned short* Wqt = vb + TENS;               // bf16 [N,K]
    unsigned short* Wkt = Wqt + WE;
    unsigned short* Wvt = Wkt + WE;
    unsigned short* Wot = Wvt + WE;
    unsigned short* Qh  = Wot + WE;                // bf16 [B,H,S,D]
    unsigned short* Kh  = Qh + TENS;
    unsigned short* Vt  = Kh + TENS;               // bf16 [B,H,D,S]
    unsigned short* An  = Vt + TENS;               // bf16 [B,S,E]

    prep_k<<<dim3(7168), 256, 0, stream>>>(q, k, v, qb, kb, vb,
                                           Wq, Wk, Wv, Wo, Wqt, Wkt, Wvt, Wot);
    proj_gemm_k<<<dim3(768), 256, 0, stream>>>(
        qb, kb, vb, Wqt, Wkt, Wvt, bq, bk, bv, Qh, Kh, Vt);
    attn_mfma_k<<<dim3(512), 512, 0, stream>>>(Qh, Kh, Vt, An);
    out_gemm_k<<<dim3(512), 256, 0, stream>>>(An, Wot, bo, (float*)d_out);
}

// Round 6
// 211.829 us; speedup vs baseline: 1.0593x; 1.0593x over previous
//
#include <hip/hip_runtime.h>
#include <math.h>

#define Bd 2
#define Sd 2048
#define Ed 1024
#define Hd 16
#define Dd 64
#define Md (Bd * Sd)     // 4096
#define Kd 1024          // GEMM K == E
#define Nd 1024          // GEMM N == E

typedef __attribute__((ext_vector_type(8))) short bf16x8;
typedef __attribute__((ext_vector_type(4))) float f32x4;

__device__ __forceinline__ unsigned short f2bf(float f) {   // RNE (epilogues)
    unsigned x = __float_as_uint(f);
    x += 0x7fffu + ((x >> 16) & 1u);
    return (unsigned short)(x >> 16);
}

// round-half-up bf16 pack of two floats -> one dword via v_perm_b32
__device__ __forceinline__ unsigned pk_bf16_rhu(float a, float b) {
    return __builtin_amdgcn_perm(__float_as_uint(b) + 0x8000u,
                                 __float_as_uint(a) + 0x8000u, 0x07060302u);
}

__device__ __forceinline__ void gl2lds16(const unsigned short* g, unsigned short* l) {
    // 16B-per-lane async global->LDS (global_load_lds_dwordx4).
    __builtin_amdgcn_global_load_lds(
        (__attribute__((address_space(1))) void*)g,
        (__attribute__((address_space(3))) void*)l, 16, 0, 0);
}

// ---------------------------------------------------------------------------
// Prep kernel: fused cvt3 (q/k/v fp32->bf16) + wtrans (4x weight T+cvt).
// NOTE (r8, r13): fusing the q/k/v cvt into the proj K-loop fails at any
// register-pipeline depth — keep it as a separate bandwidth-bound pass.
// ---------------------------------------------------------------------------
__global__ __launch_bounds__(256) void prep_k(
    const float* __restrict__ q, const float* __restrict__ k, const float* __restrict__ v,
    unsigned short* __restrict__ qb, unsigned short* __restrict__ kb,
    unsigned short* __restrict__ vb,
    const float* __restrict__ w0, const float* __restrict__ w1,
    const float* __restrict__ w2, const float* __restrict__ w3,
    unsigned short* __restrict__ o0, unsigned short* __restrict__ o1,
    unsigned short* __restrict__ o2, unsigned short* __restrict__ o3)
{
    const int bx = blockIdx.x;
    if (bx < 3072) {
        const int zz = bx >> 10;            // tensor 0..2
        const int blk = bx & 1023;
        const float* s = zz == 0 ? q : zz == 1 ? k : v;
        unsigned short* d = zz == 0 ? qb : zz == 1 ? kb : vb;
        const int n4 = (Bd * Sd * Ed) / 4;  // float4 count
        int i = blk * 256 + threadIdx.x;
        for (; i < n4; i += 1024 * 256) {
            float4 x = ((const float4*)s)[i];
            uint2 u = make_uint2(pk_bf16_rhu(x.x, x.y), pk_bf16_rhu(x.z, x.w));
            ((uint2*)d)[i] = u;
        }
        return;
    }
    __shared__ unsigned short Tl[32][36];
    const int idx = bx - 3072;              // 0..4095
    const int z   = idx >> 10;              // weight 0..3
    const int ky  = (idx >> 5) & 31;
    const int nx  = idx & 31;
    const float* W = z == 0 ? w0 : z == 1 ? w1 : z == 2 ? w2 : w3;
    unsigned short* Wt = z == 0 ? o0 : z == 1 ? o1 : z == 2 ? o2 : o3;

    const int t = threadIdx.x;
    const int r = t >> 3;
    const int c4 = (t & 7) * 4;
    const int k0 = ky * 32;
    const int n0 = nx * 32;

    float4 x = *(const float4*)(W + (size_t)(k0 + r) * Nd + n0 + c4);
    Tl[c4 + 0][r] = f2bf(x.x);
    Tl[c4 + 1][r] = f2bf(x.y);
    Tl[c4 + 2][r] = f2bf(x.z);
    Tl[c4 + 3][r] = f2bf(x.w);
    __syncthreads();
    ushort4 u = make_ushort4(Tl[r][c4 + 0], Tl[r][c4 + 1], Tl[r][c4 + 2], Tl[r][c4 + 3]);
    *(ushort4*)(Wt + (size_t)(n0 + r) * Kd + k0 + c4) = u;
}

// ---------------------------------------------------------------------------
// bf16 MFMA GEMM: C = A @ Bt^T (+bias)*oscale.  AMx128 tile (AM=128|64),
// BK=32, double-buffered LDS, ONE barrier per K-iter; staging via
// global_load_lds width-16 (full-iteration async depth).
// mode 0: fp32 flat [M,N];  mode 1: bf16 [B,H,S,D];  mode 2: bf16 [B,H,D,S]
// ---------------------------------------------------------------------------
template <int AM>
__device__ __forceinline__ void gemm_v5(
    const unsigned short* __restrict__ A, const unsigned short* __restrict__ Bt,
    const float* __restrict__ bias, void* __restrict__ Yv,
    int m0, int n0, int mode, float oscale)
{
    constexpr int AMT = AM / 32;               // per-wave m mfma tiles (4|2)
    __shared__ unsigned short As[2][AM * 32];
    __shared__ unsigned short Bs[2][128 * 32];

    const int tid  = threadIdx.x;
    const int w    = tid >> 6;
    const int lane = tid & 63;
    const int ln   = lane & 15;
    const int quad = lane >> 4;
    const int wm = (w >> 1) * (AM / 2);
    const int wn = (w & 1) * 64;

    const int lrow = lane >> 2;        // 0..15
    const int lcol = (lane & 3) * 8;   // element offset (8 bf16 per lane)

    const unsigned short* Bg0 = Bt + (size_t)(n0 + (2 * w) * 16 + lrow) * Kd + lcol;
    const unsigned short* Bg1 = Bg0 + 16 * Kd;
    const int aseg = (AM == 128) ? 2 * w : w;
    const unsigned short* Ag0 = A + (size_t)(m0 + aseg * 16 + lrow) * Kd + lcol;
    const unsigned short* Ag1 = Ag0 + 16 * Kd;

    f32x4 acc[AMT][4];
    #pragma unroll
    for (int i = 0; i < AMT; ++i)
        #pragma unroll
        for (int j = 0; j < 4; ++j)
            acc[i][j] = (f32x4){0.f, 0.f, 0.f, 0.f};

    gl2lds16(Bg0, &Bs[0][(2 * w) * 512]);
    gl2lds16(Bg1, &Bs[0][(2 * w) * 512 + 512]);
    gl2lds16(Ag0, &As[0][aseg * 512]);
    if constexpr (AM == 128) gl2lds16(Ag1, &As[0][aseg * 512 + 512]);

    for (int k0 = 0; k0 < Kd; k0 += 32) {
        const int buf = (k0 >> 5) & 1;
        __syncthreads();   // drains staging of buf; reads of buf^1 complete

        if (k0 + 32 < Kd) {   // prefetch next iter into buf^1 (full-iter slack)
            gl2lds16(Bg0 + k0 + 32, &Bs[buf ^ 1][(2 * w) * 512]);
            gl2lds16(Bg1 + k0 + 32, &Bs[buf ^ 1][(2 * w) * 512 + 512]);
            gl2lds16(Ag0 + k0 + 32, &As[buf ^ 1][aseg * 512]);
            if constexpr (AM == 128)
                gl2lds16(Ag1 + k0 + 32, &As[buf ^ 1][aseg * 512 + 512]);
        }

        bf16x8 af[AMT], bfr[4];
        #pragma unroll
        for (int mi = 0; mi < AMT; ++mi)
            af[mi] = *(const bf16x8*)(&As[buf][(wm + mi * 16 + ln) * 32 + quad * 8]);
        #pragma unroll
        for (int ni = 0; ni < 4; ++ni)
            bfr[ni] = *(const bf16x8*)(&Bs[buf][(wn + ni * 16 + ln) * 32 + quad * 8]);
        #pragma unroll
        for (int mi = 0; mi < AMT; ++mi)
            #pragma unroll
            for (int ni = 0; ni < 4; ++ni)
                acc[mi][ni] = __builtin_amdgcn_mfma_f32_16x16x32_bf16(
                    af[mi], bfr[ni], acc[mi][ni], 0, 0, 0);
    }

    float bval[4];
    #pragma unroll
    for (int ni = 0; ni < 4; ++ni) bval[ni] = bias[n0 + wn + ni * 16 + ln];

    if (mode == 0) {
        float* Y = (float*)Yv;
        #pragma unroll
        for (int mi = 0; mi < AMT; ++mi) {
            #pragma unroll
            for (int ni = 0; ni < 4; ++ni) {
                int n = n0 + wn + ni * 16 + ln;
                #pragma unroll
                for (int r = 0; r < 4; ++r) {
                    int m = m0 + wm + mi * 16 + quad * 4 + r;
                    Y[(size_t)m * Nd + n] = (acc[mi][ni][r] + bval[ni]) * oscale;
                }
            }
        }
    } else if (mode == 1) {
        unsigned short* Y = (unsigned short*)Yv;
        #pragma unroll
        for (int mi = 0; mi < AMT; ++mi) {
            #pragma unroll
            for (int ni = 0; ni < 4; ++ni) {
                int n = n0 + wn + ni * 16 + ln;
                int h = n >> 6, d = n & 63;
                #pragma unroll
                for (int r = 0; r < 4; ++r) {
                    int m = m0 + wm + mi * 16 + quad * 4 + r;
                    int b = m >> 11, s = m & 2047;
                    Y[(((size_t)b * Hd + h) * Sd + s) * Dd + d] =
                        f2bf((acc[mi][ni][r] + bval[ni]) * oscale);
                }
            }
        }
    } else {
        unsigned short* Y = (unsigned short*)Yv;
        #pragma unroll
        for (int mi = 0; mi < AMT; ++mi) {
            int mbase = m0 + wm + mi * 16 + quad * 4;
            int b = mbase >> 11, s = mbase & 2047;
            #pragma unroll
            for (int ni = 0; ni < 4; ++ni) {
                int n = n0 + wn + ni * 16 + ln;
                int h = n >> 6, d = n & 63;
                ushort4 u = make_ushort4(
                    f2bf((acc[mi][ni][0] + bval[ni]) * oscale),
                    f2bf((acc[mi][ni][1] + bval[ni]) * oscale),
                    f2bf((acc[mi][ni][2] + bval[ni]) * oscale),
                    f2bf((acc[mi][ni][3] + bval[ni]) * oscale));
                *(ushort4*)(Y + (((size_t)b * Hd + h) * Dd + d) * Sd + s) = u;
            }
        }
    }
}

// Q/K/V projection (bf16 A).  Flat 768-block grid, XCD-aware decode.
__global__ __launch_bounds__(256) void proj_gemm_k(
    const unsigned short* A0, const unsigned short* A1, const unsigned short* A2,
    const unsigned short* B0, const unsigned short* B1, const unsigned short* B2,
    const float* b0, const float* b1, const float* b2,
    unsigned short* Y0, unsigned short* Y1, unsigned short* Y2)
{
    const int l    = blockIdx.x;
    const int xcd  = l & 7;
    const int g    = l >> 3;          // 0..95
    const int n_t  = g & 7;
    const int msub = (g >> 3) & 3;
    const int z    = g >> 5;          // 0..2
    const int m_t  = xcd * 4 + msub;

    const unsigned short* A = z == 0 ? A0 : z == 1 ? A1 : A2;
    const unsigned short* B = z == 0 ? B0 : z == 1 ? B1 : B2;
    const float* bias       = z == 0 ? b0 : z == 1 ? b1 : b2;
    unsigned short* Y       = z == 0 ? Y0 : z == 1 ? Y1 : Y2;
    gemm_v5<128>(A, B, bias, Y, m_t * 128, n_t * 128,
                 z == 2 ? 2 : 1,
                 z == 0 ? 0.18033688011112042f : 1.0f);  // 0.125*log2(e)
}

// Output projection: 64x128 tiles -> 512 blocks (2/CU), XCD swizzle.
__global__ __launch_bounds__(256) void out_gemm_k(
    const unsigned short* A, const unsigned short* Bt, const float* bias, float* Y)
{
    const int l    = blockIdx.x;
    const int xcd  = l & 7;
    const int g    = l >> 3;          // 0..63
    const int n_t  = g & 7;
    const int msub = g >> 3;          // 0..7
    const int m_t  = xcd * 8 + msub;  // 0..63 (64-row tiles)
    gemm_v5<64>(A, Bt, bias, Y, m_t * 64, n_t * 128, 0, 1.0f);
}

// ---------------------------------------------------------------------------
// Flash-style causal attention, r21: r18's dual-q 4-wave body EXACTLY, but
// ONE subtile per barrier group and a 40 KB LDS footprint:
//   Ks[2][64*64] 16K + Vs[2][64*64] 16K + swizzled Pt[4][16][64] 8K = 40960B
//   -> 4 blocks/CU (4 x 40960 = 160 KiB exactly), 16 waves/CU, 4 waves/SIMD
//   at the natural VGPR ~112.  Rationale: r18 is latency-bound at 2 blocks/CU
//   (per-SIMD issue ~28%); doubling residency hides the per-barrier fixed
//   cost (m114 wave-level overlap).  Barriers double (nsub vs ngrp) — that
//   is the bet; staging bytes unchanged.
// LESSONS CARVED IN STONE:
//   - r16/r17: direct-global K/V loads get sunk by the compiler (VGPR 48/72)
//     -> serialized L2 latency.  All K/V via global_load_lds only.
//   - r19: ANY __launch_bounds__ min-waves arg flips allocator into
//     minimize-VGPR mode -> spills (WRITE_SIZE 8->83 MB).  Never pass it.
//   - r20: key-split 8-wave + end-merge FAILED correctness on a pure
//     launch-bounds change (latent scheduling-dependent race, unexplained).
//     The key-split structure is RETIRED; do not resurrect without a
//     race-free redesign.  Swizzled Pt itself is proven (r19 passed).
// ---------------------------------------------------------------------------
__global__ __launch_bounds__(256) void attn_mfma_k(
    const unsigned short* __restrict__ Qg,   // [B,H,S,D] bf16, pre-scaled
    const unsigned short* __restrict__ Kg,   // [B,H,S,D] bf16
    const unsigned short* __restrict__ Vg,   // [B,H,D,S] bf16
    unsigned short* __restrict__ Aout)       // [B,S,E] bf16
{
    __shared__ unsigned short Ks[2][64 * 64];   // 16 KB double-buffer
    __shared__ unsigned short Vs[2][64 * 64];   // 16 KB double-buffer
    __shared__ unsigned short Pt[4][16][64];    // 8 KB, XOR-swizzled (r19)

    const int tid  = threadIdx.x;
    const int w    = tid >> 6;
    const int lane = tid & 63;
    const int ln   = lane & 15;
    const int quad = lane >> 4;

    const int l   = blockIdx.x;               // 0..511
    const int bh  = (l & 7) * 4 + ((l >> 3) & 3);
    const int qtA = l >> 5;                   // 0..15 (heaviest staging first)
    const int qtB = 31 - qtA;                 // 16..31
    const int b   = bh >> 4;
    const int h   = bh & 15;

    const size_t baseQK = (size_t)bh * Sd * Dd;
    const size_t baseV  = (size_t)bh * Dd * Sd;
    const f32x4 vzero = {0.f, 0.f, 0.f, 0.f};

    const int nsub = qtB + 1;                 // staged subtiles: 17..32

    const int sr = lane >> 3;
    const int sc = ((lane & 7) ^ sr) * 8;
    const int rb0 = w * 16, rb1 = w * 16 + 8;
    const int swl = ln & 7;
    const int c0 = ((quad    ) ^ swl) * 8;
    const int c1 = ((quad + 4) ^ swl) * 8;
    const int pswz = swl << 3;                // Pt element-XOR swizzle (r19)

    const int qrowA = qtA * 64 + w * 16;
    const int qrowB = qtB * 64 + w * 16;
    const int qgA = qrowA + ln, qgB = qrowB + ln;
    const unsigned short* qpA = Qg + baseQK + (size_t)qgA * Dd + 8 * quad;
    const unsigned short* qpB = Qg + baseQK + (size_t)qgB * Dd + 8 * quad;
    const bf16x8 qA0 = *(const bf16x8*)(qpA), qA1 = *(const bf16x8*)(qpA + 32);
    const bf16x8 qB0 = *(const bf16x8*)(qpB), qB1 = *(const bf16x8*)(qpB + 32);

    float lA = 0.f, lB = 0.f;
    f32x4 OA[4], OB[4];
    #pragma unroll
    for (int t = 0; t < 4; ++t) { OA[t] = vzero; OB[t] = vzero; }

    const unsigned short* Kst0 = Kg + baseQK + (size_t)(rb0 + sr) * Dd + sc;
    const unsigned short* Kst1 = Kg + baseQK + (size_t)(rb1 + sr) * Dd + sc;
    const unsigned short* Vst0 = Vg + baseV  + (size_t)(rb0 + sr) * Sd + sc;
    const unsigned short* Vst1 = Vg + baseV  + (size_t)(rb1 + sr) * Sd + sc;
    unsigned short* Ptw = &Pt[w][ln][0];

    // prologue: stage subtile 0 into buffer 0
    gl2lds16(Kst0, &Ks[0][rb0 * 64]);
    gl2lds16(Kst1, &Ks[0][rb1 * 64]);
    gl2lds16(Vst0, &Vs[0][rb0 * 64]);
    gl2lds16(Vst1, &Vs[0][rb1 * 64]);

    for (int it = 0; it < nsub; ++it) {
        const int cur = it & 1;
        __syncthreads();   // drains staging of buf[cur]; prev reads complete

        if (it + 1 < nsub) {   // prefetch subtile it+1 into buf[cur^1]
            const int nk = (it + 1) * 64;
            gl2lds16(Kst0 + (size_t)nk * Dd, &Ks[cur ^ 1][rb0 * 64]);
            gl2lds16(Kst1 + (size_t)nk * Dd, &Ks[cur ^ 1][rb1 * 64]);
            gl2lds16(Vst0 + nk, &Vs[cur ^ 1][rb0 * 64]);
            gl2lds16(Vst1 + nk, &Vs[cur ^ 1][rb1 * 64]);
        }

        const int nk  = it * 64;
        const bool doA = (it <= qtA);          // block-uniform

        // K fragments once; feed BOTH q-tiles' QK^T
        bf16x8 kf0[4], kf1[4];
        #pragma unroll
        for (int t = 0; t < 4; ++t) {
            const int R = (t * 16 + ln) * 64;
            kf0[t] = *(const bf16x8*)&Ks[cur][R + c0];
            kf1[t] = *(const bf16x8*)&Ks[cur][R + c1];
        }

        f32x4 SB[4], SA[4];
        #pragma unroll
        for (int t = 0; t < 4; ++t) {
            f32x4 z = __builtin_amdgcn_mfma_f32_16x16x32_bf16(kf0[t], qB0, vzero, 0, 0, 0);
            SB[t]   = __builtin_amdgcn_mfma_f32_16x16x32_bf16(kf1[t], qB1, z,     0, 0, 0);
        }
        if (doA) {
            #pragma unroll
            for (int t = 0; t < 4; ++t) {
                f32x4 z = __builtin_amdgcn_mfma_f32_16x16x32_bf16(kf0[t], qA0, vzero, 0, 0, 0);
                SA[t]   = __builtin_amdgcn_mfma_f32_16x16x32_bf16(kf1[t], qA1, z,     0, 0, 0);
            }
        }

        if (it == qtB) {   // diagonal for tile B (last subtile)
            #pragma unroll
            for (int t = 0; t < 4; ++t)
                #pragma unroll
                for (int r = 0; r < 4; ++r)
                    if (nk + t * 16 + quad * 4 + r > qgB)
                        SB[t][r] = -1e30f;
        }
        if (doA && it == qtA) {   // diagonal for tile A
            #pragma unroll
            for (int t = 0; t < 4; ++t)
                #pragma unroll
                for (int r = 0; r < 4; ++r)
                    if (nk + t * 16 + quad * 4 + r > qgA)
                        SA[t][r] = -1e30f;
        }

        // softmax B -> pfB via wave-private swizzled Pt (no barrier)
        {
            float p[16]; float rsum = 0.f;
            #pragma unroll
            for (int t = 0; t < 4; ++t)
                #pragma unroll
                for (int r = 0; r < 4; ++r) {
                    float e = __builtin_amdgcn_exp2f(SB[t][r]);
                    p[t * 4 + r] = e; rsum += e;
                }
            lB += rsum;
            #pragma unroll
            for (int t = 0; t < 4; ++t) {
                uint2 u = make_uint2(pk_bf16_rhu(p[t * 4 + 0], p[t * 4 + 1]),
                                     pk_bf16_rhu(p[t * 4 + 2], p[t * 4 + 3]));
                *(uint2*)&Ptw[(t * 16 + quad * 4) ^ pswz] = u;
            }
        }
        const bf16x8 pfB0 = *(const bf16x8*)&Ptw[(8 * quad) ^ pswz];
        const bf16x8 pfB1 = *(const bf16x8*)&Ptw[(32 + 8 * quad) ^ pswz];

        // softmax A -> pfA (Pt reused after pfB reads; same-wave order)
        bf16x8 pfA0, pfA1;
        if (doA) {
            float p[16]; float rsum = 0.f;
            #pragma unroll
            for (int t = 0; t < 4; ++t)
                #pragma unroll
                for (int r = 0; r < 4; ++r) {
                    float e = __builtin_amdgcn_exp2f(SA[t][r]);
                    p[t * 4 + r] = e; rsum += e;
                }
            lA += rsum;
            #pragma unroll
            for (int t = 0; t < 4; ++t) {
                uint2 u = make_uint2(pk_bf16_rhu(p[t * 4 + 0], p[t * 4 + 1]),
                                     pk_bf16_rhu(p[t * 4 + 2], p[t * 4 + 3]));
                *(uint2*)&Ptw[(t * 16 + quad * 4) ^ pswz] = u;
            }
            pfA0 = *(const bf16x8*)&Ptw[(8 * quad) ^ pswz];
            pfA1 = *(const bf16x8*)&Ptw[(32 + 8 * quad) ^ pswz];
        }

        // V fragments once; feed BOTH q-tiles' PV
        #pragma unroll
        for (int t = 0; t < 4; ++t) {
            const int R = (t * 16 + ln) * 64;
            bf16x8 v0 = *(const bf16x8*)&Vs[cur][R + c0];
            bf16x8 v1 = *(const bf16x8*)&Vs[cur][R + c1];
            OB[t] = __builtin_amdgcn_mfma_f32_16x16x32_bf16(v0, pfB0, OB[t], 0, 0, 0);
            OB[t] = __builtin_amdgcn_mfma_f32_16x16x32_bf16(v1, pfB1, OB[t], 0, 0, 0);
            if (doA) {
                OA[t] = __builtin_amdgcn_mfma_f32_16x16x32_bf16(v0, pfA0, OA[t], 0, 0, 0);
                OA[t] = __builtin_amdgcn_mfma_f32_16x16x32_bf16(v1, pfA1, OA[t], 0, 0, 0);
            }
        }

        if (doA && it == qtA) {   // tile-A epilogue (A complete)
            float l_run = lA;
            l_run += __shfl_xor(l_run, 16);
            l_run += __shfl_xor(l_run, 32);
            float inv = 1.f / l_run;
            unsigned short* op =
                Aout + ((size_t)b * Sd + qgA) * Ed + h * 64 + quad * 4;
            #pragma unroll
            for (int t = 0; t < 4; ++t) {
                ushort4 u = make_ushort4(f2bf(OA[t][0] * inv), f2bf(OA[t][1] * inv),
                                         f2bf(OA[t][2] * inv), f2bf(OA[t][3] * inv));
                *(ushort4*)(op + t * 16) = u;
            }
        }
    }

    float l_run = lB;
    l_run += __shfl_xor(l_run, 16);
    l_run += __shfl_xor(l_run, 32);
    float inv = 1.f / l_run;
    unsigned short* op = Aout + ((size_t)b * Sd + qgB) * Ed + h * 64 + quad * 4;
    #pragma unroll
    for (int t = 0; t < 4; ++t) {
        ushort4 u = make_ushort4(f2bf(OB[t][0] * inv), f2bf(OB[t][1] * inv),
                                 f2bf(OB[t][2] * inv), f2bf(OB[t][3] * inv));
        *(ushort4*)(op + t * 16) = u;
    }
}

// ---------------------------------------------------------------------------
extern "C" void kernel_launch(void* const* d_in, const int* in_sizes, int n_in,
                              void* d_out, int out_size, void* d_ws, size_t ws_size,
                              hipStream_t stream) {
    const float* q  = (const float*)d_in[0];
    const float* k  = (const float*)d_in[1];
    const float* v  = (const float*)d_in[2];
    const float* Wq = (const float*)d_in[3];
    const float* bq = (const float*)d_in[4];
    const float* Wk = (const float*)d_in[5];
    const float* bk = (const float*)d_in[6];
    const float* Wv = (const float*)d_in[7];
    const float* bv = (const float*)d_in[8];
    const float* Wo = (const float*)d_in[9];
    const float* bo = (const float*)d_in[10];

    const size_t TENS = (size_t)Bd * Sd * Ed;  // 4,194,304
    const size_t WE   = (size_t)Ed * Ed;       // 1,048,576
    unsigned short* qb  = (unsigned short*)d_ws;   // bf16 [M,K]
    unsigned short* kb  = qb + TENS;
    unsigned short* vb  = kb + TENS;
    unsigned short* Wqt = vb + TENS;               // bf16 [N,K]
    unsigned short* Wkt = Wqt + WE;
    unsigned short* Wvt = Wkt + WE;
    unsigned short* Wot = Wvt + WE;
    unsigned short* Qh  = Wot + WE;                // bf16 [B,H,S,D]
    unsigned short* Kh  = Qh + TENS;
    unsigned short* Vt  = Kh + TENS;               // bf16 [B,H,D,S]
    unsigned short* An  = Vt + TENS;               // bf16 [B,S,E]

    prep_k<<<dim3(7168), 256, 0, stream>>>(q, k, v, qb, kb, vb,
                                           Wq, Wk, Wv, Wo, Wqt, Wkt, Wvt, Wot);
    proj_gemm_k<<<dim3(768), 256, 0, stream>>>(
        qb, kb, vb, Wqt, Wkt, Wvt, bq, bk, bv, Qh, Kh, Vt);
    attn_mfma_k<<<dim3(512), 256, 0, stream>>>(Qh, Kh, Vt, An);
    out_gemm_k<<<dim3(512), 256, 0, stream>>>(An, Wot, bo, (float*)d_out);
}

// Round 8
// 198.532 us; speedup vs baseline: 1.1303x; 1.0670x over previous
//
#include <hip/hip_runtime.h>
#include <math.h>

#define Bd 2
#define Sd 2048
#define Ed 1024
#define Hd 16
#define Dd 64
#define Md (Bd * Sd)     // 4096
#define Kd 1024          // GEMM K == E
#define Nd 1024          // GEMM N == E

typedef __attribute__((ext_vector_type(8))) short bf16x8;
typedef __attribute__((ext_vector_type(4))) float f32x4;

__device__ __forceinline__ unsigned short f2bf(float f) {   // RNE (epilogues)
    unsigned x = __float_as_uint(f);
    x += 0x7fffu + ((x >> 16) & 1u);
    return (unsigned short)(x >> 16);
}

// round-half-up bf16 pack of two floats -> one dword via v_perm_b32
__device__ __forceinline__ unsigned pk_bf16_rhu(float a, float b) {
    return __builtin_amdgcn_perm(__float_as_uint(b) + 0x8000u,
                                 __float_as_uint(a) + 0x8000u, 0x07060302u);
}

__device__ __forceinline__ void gl2lds16(const unsigned short* g, unsigned short* l) {
    // 16B-per-lane async global->LDS (global_load_lds_dwordx4).
    __builtin_amdgcn_global_load_lds(
        (__attribute__((address_space(1))) void*)g,
        (__attribute__((address_space(3))) void*)l, 16, 0, 0);
}

// ---------------------------------------------------------------------------
// Prep kernel: fused cvt3 (q/k/v fp32->bf16) + wtrans (4x weight T+cvt).
// NOTE (r8, r13): fusing the q/k/v cvt into the proj K-loop fails at any
// register-pipeline depth — keep it as a separate bandwidth-bound pass.
// ---------------------------------------------------------------------------
__global__ __launch_bounds__(256) void prep_k(
    const float* __restrict__ q, const float* __restrict__ k, const float* __restrict__ v,
    unsigned short* __restrict__ qb, unsigned short* __restrict__ kb,
    unsigned short* __restrict__ vb,
    const float* __restrict__ w0, const float* __restrict__ w1,
    const float* __restrict__ w2, const float* __restrict__ w3,
    unsigned short* __restrict__ o0, unsigned short* __restrict__ o1,
    unsigned short* __restrict__ o2, unsigned short* __restrict__ o3)
{
    const int bx = blockIdx.x;
    if (bx < 3072) {
        const int zz = bx >> 10;            // tensor 0..2
        const int blk = bx & 1023;
        const float* s = zz == 0 ? q : zz == 1 ? k : v;
        unsigned short* d = zz == 0 ? qb : zz == 1 ? kb : vb;
        const int n4 = (Bd * Sd * Ed) / 4;  // float4 count
        int i = blk * 256 + threadIdx.x;
        for (; i < n4; i += 1024 * 256) {
            float4 x = ((const float4*)s)[i];
            uint2 u = make_uint2(pk_bf16_rhu(x.x, x.y), pk_bf16_rhu(x.z, x.w));
            ((uint2*)d)[i] = u;
        }
        return;
    }
    __shared__ unsigned short Tl[32][36];
    const int idx = bx - 3072;              // 0..4095
    const int z   = idx >> 10;              // weight 0..3
    const int ky  = (idx >> 5) & 31;
    const int nx  = idx & 31;
    const float* W = z == 0 ? w0 : z == 1 ? w1 : z == 2 ? w2 : w3;
    unsigned short* Wt = z == 0 ? o0 : z == 1 ? o1 : z == 2 ? o2 : o3;

    const int t = threadIdx.x;
    const int r = t >> 3;
    const int c4 = (t & 7) * 4;
    const int k0 = ky * 32;
    const int n0 = nx * 32;

    float4 x = *(const float4*)(W + (size_t)(k0 + r) * Nd + n0 + c4);
    Tl[c4 + 0][r] = f2bf(x.x);
    Tl[c4 + 1][r] = f2bf(x.y);
    Tl[c4 + 2][r] = f2bf(x.z);
    Tl[c4 + 3][r] = f2bf(x.w);
    __syncthreads();
    ushort4 u = make_ushort4(Tl[r][c4 + 0], Tl[r][c4 + 1], Tl[r][c4 + 2], Tl[r][c4 + 3]);
    *(ushort4*)(Wt + (size_t)(n0 + r) * Kd + k0 + c4) = u;
}

// ---------------------------------------------------------------------------
// bf16 MFMA GEMM: C = A @ Bt^T (+bias)*oscale.  AMx128 tile (AM=128|64),
// BK=32, double-buffered LDS, ONE barrier per K-iter; staging via
// global_load_lds width-16 (full-iteration async depth).
// mode 0: fp32 flat [M,N];  mode 1: bf16 [B,H,S,D];  mode 2: bf16 [B,H,D,S]
// ---------------------------------------------------------------------------
template <int AM>
__device__ __forceinline__ void gemm_v5(
    const unsigned short* __restrict__ A, const unsigned short* __restrict__ Bt,
    const float* __restrict__ bias, void* __restrict__ Yv,
    int m0, int n0, int mode, float oscale)
{
    constexpr int AMT = AM / 32;               // per-wave m mfma tiles (4|2)
    __shared__ unsigned short As[2][AM * 32];
    __shared__ unsigned short Bs[2][128 * 32];

    const int tid  = threadIdx.x;
    const int w    = tid >> 6;
    const int lane = tid & 63;
    const int ln   = lane & 15;
    const int quad = lane >> 4;
    const int wm = (w >> 1) * (AM / 2);
    const int wn = (w & 1) * 64;

    const int lrow = lane >> 2;        // 0..15
    const int lcol = (lane & 3) * 8;   // element offset (8 bf16 per lane)

    const unsigned short* Bg0 = Bt + (size_t)(n0 + (2 * w) * 16 + lrow) * Kd + lcol;
    const unsigned short* Bg1 = Bg0 + 16 * Kd;
    const int aseg = (AM == 128) ? 2 * w : w;
    const unsigned short* Ag0 = A + (size_t)(m0 + aseg * 16 + lrow) * Kd + lcol;
    const unsigned short* Ag1 = Ag0 + 16 * Kd;

    f32x4 acc[AMT][4];
    #pragma unroll
    for (int i = 0; i < AMT; ++i)
        #pragma unroll
        for (int j = 0; j < 4; ++j)
            acc[i][j] = (f32x4){0.f, 0.f, 0.f, 0.f};

    gl2lds16(Bg0, &Bs[0][(2 * w) * 512]);
    gl2lds16(Bg1, &Bs[0][(2 * w) * 512 + 512]);
    gl2lds16(Ag0, &As[0][aseg * 512]);
    if constexpr (AM == 128) gl2lds16(Ag1, &As[0][aseg * 512 + 512]);

    for (int k0 = 0; k0 < Kd; k0 += 32) {
        const int buf = (k0 >> 5) & 1;
        __syncthreads();   // drains staging of buf; reads of buf^1 complete

        if (k0 + 32 < Kd) {   // prefetch next iter into buf^1 (full-iter slack)
            gl2lds16(Bg0 + k0 + 32, &Bs[buf ^ 1][(2 * w) * 512]);
            gl2lds16(Bg1 + k0 + 32, &Bs[buf ^ 1][(2 * w) * 512 + 512]);
            gl2lds16(Ag0 + k0 + 32, &As[buf ^ 1][aseg * 512]);
            if constexpr (AM == 128)
                gl2lds16(Ag1 + k0 + 32, &As[buf ^ 1][aseg * 512 + 512]);
        }

        bf16x8 af[AMT], bfr[4];
        #pragma unroll
        for (int mi = 0; mi < AMT; ++mi)
            af[mi] = *(const bf16x8*)(&As[buf][(wm + mi * 16 + ln) * 32 + quad * 8]);
        #pragma unroll
        for (int ni = 0; ni < 4; ++ni)
            bfr[ni] = *(const bf16x8*)(&Bs[buf][(wn + ni * 16 + ln) * 32 + quad * 8]);
        #pragma unroll
        for (int mi = 0; mi < AMT; ++mi)
            #pragma unroll
            for (int ni = 0; ni < 4; ++ni)
                acc[mi][ni] = __builtin_amdgcn_mfma_f32_16x16x32_bf16(
                    af[mi], bfr[ni], acc[mi][ni], 0, 0, 0);
    }

    float bval[4];
    #pragma unroll
    for (int ni = 0; ni < 4; ++ni) bval[ni] = bias[n0 + wn + ni * 16 + ln];

    if (mode == 0) {
        float* Y = (float*)Yv;
        #pragma unroll
        for (int mi = 0; mi < AMT; ++mi) {
            #pragma unroll
            for (int ni = 0; ni < 4; ++ni) {
                int n = n0 + wn + ni * 16 + ln;
                #pragma unroll
                for (int r = 0; r < 4; ++r) {
                    int m = m0 + wm + mi * 16 + quad * 4 + r;
                    Y[(size_t)m * Nd + n] = (acc[mi][ni][r] + bval[ni]) * oscale;
                }
            }
        }
    } else if (mode == 1) {
        unsigned short* Y = (unsigned short*)Yv;
        #pragma unroll
        for (int mi = 0; mi < AMT; ++mi) {
            #pragma unroll
            for (int ni = 0; ni < 4; ++ni) {
                int n = n0 + wn + ni * 16 + ln;
                int h = n >> 6, d = n & 63;
                #pragma unroll
                for (int r = 0; r < 4; ++r) {
                    int m = m0 + wm + mi * 16 + quad * 4 + r;
                    int b = m >> 11, s = m & 2047;
                    Y[(((size_t)b * Hd + h) * Sd + s) * Dd + d] =
                        f2bf((acc[mi][ni][r] + bval[ni]) * oscale);
                }
            }
        }
    } else {
        unsigned short* Y = (unsigned short*)Yv;
        #pragma unroll
        for (int mi = 0; mi < AMT; ++mi) {
            int mbase = m0 + wm + mi * 16 + quad * 4;
            int b = mbase >> 11, s = mbase & 2047;
            #pragma unroll
            for (int ni = 0; ni < 4; ++ni) {
                int n = n0 + wn + ni * 16 + ln;
                int h = n >> 6, d = n & 63;
                ushort4 u = make_ushort4(
                    f2bf((acc[mi][ni][0] + bval[ni]) * oscale),
                    f2bf((acc[mi][ni][1] + bval[ni]) * oscale),
                    f2bf((acc[mi][ni][2] + bval[ni]) * oscale),
                    f2bf((acc[mi][ni][3] + bval[ni]) * oscale));
                *(ushort4*)(Y + (((size_t)b * Hd + h) * Dd + d) * Sd + s) = u;
            }
        }
    }
}

// Q/K/V projection (bf16 A).  Flat 768-block grid, XCD-aware decode.
__global__ __launch_bounds__(256) void proj_gemm_k(
    const unsigned short* A0, const unsigned short* A1, const unsigned short* A2,
    const unsigned short* B0, const unsigned short* B1, const unsigned short* B2,
    const float* b0, const float* b1, const float* b2,
    unsigned short* Y0, unsigned short* Y1, unsigned short* Y2)
{
    const int l    = blockIdx.x;
    const int xcd  = l & 7;
    const int g    = l >> 3;          // 0..95
    const int n_t  = g & 7;
    const int msub = (g >> 3) & 3;
    const int z    = g >> 5;          // 0..2
    const int m_t  = xcd * 4 + msub;

    const unsigned short* A = z == 0 ? A0 : z == 1 ? A1 : A2;
    const unsigned short* B = z == 0 ? B0 : z == 1 ? B1 : B2;
    const float* bias       = z == 0 ? b0 : z == 1 ? b1 : b2;
    unsigned short* Y       = z == 0 ? Y0 : z == 1 ? Y1 : Y2;
    gemm_v5<128>(A, B, bias, Y, m_t * 128, n_t * 128,
                 z == 2 ? 2 : 1,
                 z == 0 ? 0.18033688011112042f : 1.0f);  // 0.125*log2(e)
}

// Output projection: 64x128 tiles -> 512 blocks (2/CU), XCD swizzle.
__global__ __launch_bounds__(256) void out_gemm_k(
    const unsigned short* A, const unsigned short* Bt, const float* bias, float* Y)
{
    const int l    = blockIdx.x;
    const int xcd  = l & 7;
    const int g    = l >> 3;          // 0..63
    const int n_t  = g & 7;
    const int msub = g >> 3;          // 0..7
    const int m_t  = xcd * 8 + msub;  // 0..63 (64-row tiles)
    gemm_v5<64>(A, Bt, bias, Y, m_t * 64, n_t * 128, 0, 1.0f);
}

// ---------------------------------------------------------------------------
// Flash-style causal attention, r22 (tile-split 8-wave): r18's staging
// machinery (2 subtiles/barrier, K+V double-buffer, XOR swizzle) with
// 512-thread blocks: waves 0-3 own tile-B row-slices, waves 4-7 own tile-A
// row-slices of the same (qtA, qtB=31-qtA) pair.  NO cross-wave merge
// (r20's retired structure): every wave owns its q-rows end-to-end and
// writes its own output; A-waves finish at it==qtA, then only co-stage.
// Why (r21 post-mortem): occupancy = min(LDS capacity, grid/CU).  The 512-
// block grid supplies only 2 blocks/CU, so r21's 4-blocks/CU LDS shrink
// bought nothing while doubling barriers (43.3 -> 54.7us).  r22 doubles
// waves per block instead: 2 blocks/CU x 8 waves = 16 waves/CU (4/SIMD)
// IF VGPR<=128 (single-tile body < r18's dual 112 -> expect ~100).
// Per-wave critical path: ~33 dual bodies -> nsub (17..32) single bodies.
// LDS = Ks 32K + Vs 32K + Pt[8][16][64] 16K = 81920 B; x2 = 160 KiB exact.
// LESSONS CARVED IN STONE:
//   - r16/r17: direct-global K/V loads get sunk (VGPR 48/72) -> serialized
//     L2 latency.  All K/V via global_load_lds only.
//   - r19: ANY __launch_bounds__ min-waves arg -> minimize-VGPR mode ->
//     spills (WRITE_SIZE 8->83 MB).  Never pass it.
//   - r20: key-split + end-merge failed correctness (latent race). RETIRED.
//   - r21: grid-starved occupancy: capacity without dispatch is worthless.
// (r23 == r22 resubmitted: round-7 bench died on container infra, no data.)
// ---------------------------------------------------------------------------
__global__ __launch_bounds__(512) void attn_mfma_k(
    const unsigned short* __restrict__ Qg,   // [B,H,S,D] bf16, pre-scaled
    const unsigned short* __restrict__ Kg,   // [B,H,S,D] bf16
    const unsigned short* __restrict__ Vg,   // [B,H,D,S] bf16
    unsigned short* __restrict__ Aout)       // [B,S,E] bf16
{
    __shared__ unsigned short Ks[2][2][64 * 64];   // 32 KB [buf][subtile]
    __shared__ unsigned short Vs[2][2][64 * 64];   // 32 KB
    __shared__ unsigned short Pt[8][16][64];       // 16 KB, XOR-swizzled

    const int tid  = threadIdx.x;
    const int w8   = tid >> 6;          // 0..7
    const int grp  = w8 >> 2;           // 0: tile B, 1: tile A
    const int w    = w8 & 3;            // 16-row slice within the tile
    const int lane = tid & 63;
    const int ln   = lane & 15;
    const int quad = lane >> 4;

    const int l   = blockIdx.x;               // 0..511
    const int bh  = (l & 7) * 4 + ((l >> 3) & 3);
    const int qtA = l >> 5;                   // 0..15 (heaviest staging first)
    const int qtB = 31 - qtA;                 // 16..31
    const int b   = bh >> 4;
    const int h   = bh & 15;

    const size_t baseQK = (size_t)bh * Sd * Dd;
    const size_t baseV  = (size_t)bh * Dd * Sd;
    const f32x4 vzero = {0.f, 0.f, 0.f, 0.f};

    const int nsub = qtB + 1;                 // staged subtiles: 17..32
    const int ngrp = (nsub + 1) >> 1;         // barrier groups:   9..16

    // staging: each wave stages 8 rows (rw..rw+7) of each K/V subtile
    const int rw = w8 * 8;
    const int sr = lane >> 3;                 // 0..7
    const int sc = ((lane & 7) ^ sr) * 8;     // XOR-swizzled source chunk
    const int swl = ln & 7;
    const int c0 = ((quad    ) ^ swl) * 8;
    const int c1 = ((quad + 4) ^ swl) * 8;
    const int pswz = swl << 3;                // Pt element-XOR swizzle (r19)

    // this wave's q-tile
    const int myqt  = grp ? qtA : qtB;        // wave-uniform
    const int qrow  = myqt * 64 + w * 16;
    const int qglob = qrow + ln;
    const unsigned short* qp = Qg + baseQK + (size_t)qglob * Dd + 8 * quad;
    const bf16x8 q0 = *(const bf16x8*)(qp), q1 = *(const bf16x8*)(qp + 32);

    float lsum = 0.f;
    f32x4 O[4];
    #pragma unroll
    for (int t = 0; t < 4; ++t) O[t] = vzero;

    const unsigned short* Kst = Kg + baseQK + (size_t)(rw + sr) * Dd + sc;
    const unsigned short* Vst = Vg + baseV  + (size_t)(rw + sr) * Sd + sc;
    unsigned short* Ptw = &Pt[w8][ln][0];

    // prologue: stage subtiles 0,1 into buffer 0 (nsub >= 17, both exist)
    #pragma unroll
    for (int s = 0; s < 2; ++s) {
        const int nk = s * 64;
        gl2lds16(Kst + (size_t)nk * Dd, &Ks[0][s][rw * 64]);
        gl2lds16(Vst + nk,              &Vs[0][s][rw * 64]);
    }

    for (int g = 0; g < ngrp; ++g) {
        const int cur = g & 1;
        __syncthreads();   // drains staging of buf[cur]; prev reads complete

        // prefetch group g+1 (subtiles 2g+2, 2g+3) into buf[cur^1]
        if (g + 1 < ngrp) {
            #pragma unroll
            for (int s = 0; s < 2; ++s) {
                const int ts = 2 * (g + 1) + s;
                if (ts < nsub) {      // block-uniform
                    const int nk = ts * 64;
                    gl2lds16(Kst + (size_t)nk * Dd, &Ks[cur ^ 1][s][rw * 64]);
                    gl2lds16(Vst + nk,              &Vs[cur ^ 1][s][rw * 64]);
                }
            }
        }

        #pragma unroll
        for (int s = 0; s < 2; ++s) {
            const int it = 2 * g + s;
            if (it >= nsub) break;            // block-uniform
            if (it > myqt) continue;          // wave-uniform (A-waves done)
            const int nk = it * 64;

            // K fragments from LDS
            bf16x8 kf0[4], kf1[4];
            #pragma unroll
            for (int t = 0; t < 4; ++t) {
                const int R = (t * 16 + ln) * 64;
                kf0[t] = *(const bf16x8*)&Ks[cur][s][R + c0];
                kf1[t] = *(const bf16x8*)&Ks[cur][s][R + c1];
            }

            f32x4 S[4];
            #pragma unroll
            for (int t = 0; t < 4; ++t) {
                f32x4 z = __builtin_amdgcn_mfma_f32_16x16x32_bf16(kf0[t], q0, vzero, 0, 0, 0);
                S[t]    = __builtin_amdgcn_mfma_f32_16x16x32_bf16(kf1[t], q1, z,     0, 0, 0);
            }

            if (it == myqt) {   // causal mask on this tile's diagonal
                #pragma unroll
                for (int t = 0; t < 4; ++t)
                    #pragma unroll
                    for (int r = 0; r < 4; ++r)
                        if (nk + t * 16 + quad * 4 + r > qglob)
                            S[t][r] = -1e30f;
            }

            // p = exp2(S) raw — no max subtraction (data-safe; see r10)
            float p[16];
            float rsum = 0.f;
            #pragma unroll
            for (int t = 0; t < 4; ++t)
                #pragma unroll
                for (int r = 0; r < 4; ++r) {
                    float e = __builtin_amdgcn_exp2f(S[t][r]);
                    p[t * 4 + r] = e; rsum += e;
                }
            lsum += rsum;

            // P -> B-fragment layout via wave-private swizzled Pt
            #pragma unroll
            for (int t = 0; t < 4; ++t) {
                uint2 u = make_uint2(pk_bf16_rhu(p[t * 4 + 0], p[t * 4 + 1]),
                                     pk_bf16_rhu(p[t * 4 + 2], p[t * 4 + 3]));
                *(uint2*)&Ptw[(t * 16 + quad * 4) ^ pswz] = u;
            }
            const bf16x8 pf0 = *(const bf16x8*)&Ptw[(8 * quad) ^ pswz];
            const bf16x8 pf1 = *(const bf16x8*)&Ptw[(32 + 8 * quad) ^ pswz];

            #pragma unroll
            for (int t = 0; t < 4; ++t) {
                const int R = (t * 16 + ln) * 64;
                bf16x8 v0 = *(const bf16x8*)&Vs[cur][s][R + c0];
                bf16x8 v1 = *(const bf16x8*)&Vs[cur][s][R + c1];
                O[t] = __builtin_amdgcn_mfma_f32_16x16x32_bf16(v0, pf0, O[t], 0, 0, 0);
                O[t] = __builtin_amdgcn_mfma_f32_16x16x32_bf16(v1, pf1, O[t], 0, 0, 0);
            }

            if (grp == 1 && it == myqt) {   // tile-A waves: done, write out
                float l_run = lsum;
                l_run += __shfl_xor(l_run, 16);
                l_run += __shfl_xor(l_run, 32);
                float inv = 1.f / l_run;
                unsigned short* op =
                    Aout + ((size_t)b * Sd + qglob) * Ed + h * 64 + quad * 4;
                #pragma unroll
                for (int t = 0; t < 4; ++t) {
                    ushort4 u = make_ushort4(f2bf(O[t][0] * inv), f2bf(O[t][1] * inv),
                                             f2bf(O[t][2] * inv), f2bf(O[t][3] * inv));
                    *(ushort4*)(op + t * 16) = u;
                }
            }
        }
    }

    if (grp == 0) {   // tile-B waves: final epilogue
        float l_run = lsum;
        l_run += __shfl_xor(l_run, 16);
        l_run += __shfl_xor(l_run, 32);
        float inv = 1.f / l_run;
        unsigned short* op = Aout + ((size_t)b * Sd + qglob) * Ed + h * 64 + quad * 4;
        #pragma unroll
        for (int t = 0; t < 4; ++t) {
            ushort4 u = make_ushort4(f2bf(O[t][0] * inv), f2bf(O[t][1] * inv),
                                     f2bf(O[t][2] * inv), f2bf(O[t][3] * inv));
            *(ushort4*)(op + t * 16) = u;
        }
    }
}

// ---------------------------------------------------------------------------
extern "C" void kernel_launch(void* const* d_in, const int* in_sizes, int n_in,
                              void* d_out, int out_size, void* d_ws, size_t ws_size,
                              hipStream_t stream) {
    const float* q  = (const float*)d_in[0];
    const float* k  = (const float*)d_in[1];
    const float* v  = (const float*)d_in[2];
    const float* Wq = (const float*)d_in[3];
    const float* bq = (const float*)d_in[4];
    const float* Wk = (const float*)d_in[5];
    const float* bk = (const float*)d_in[6];
    const float* Wv = (const float*)d_in[7];
    const float* bv = (const float*)d_in[8];
    const float* Wo = (const float*)d_in[9];
    const float* bo = (const float*)d_in[10];

    const size_t TENS = (size_t)Bd * Sd * Ed;  // 4,194,304
    const size_t WE   = (size_t)Ed * Ed;       // 1,048,576
    unsigned short* qb  = (unsigned short*)d_ws;   // bf16 [M,K]
    unsigned short* kb  = qb + TENS;
    unsigned short* vb  = kb + TENS;
    unsigned short* Wqt = vb + TENS;               // bf16 [N,K]
    unsigned short* Wkt = Wqt + WE;
    unsigned short* Wvt = Wkt + WE;
    unsigned short* Wot = Wvt + WE;
    unsigned short* Qh  = Wot + WE;                // bf16 [B,H,S,D]
    unsigned short* Kh  = Qh + TENS;
    unsigned short* Vt  = Kh + TENS;               // bf16 [B,H,D,S]
    unsigned short* An  = Vt + TENS;               // bf16 [B,S,E]

    prep_k<<<dim3(7168), 256, 0, stream>>>(q, k, v, qb, kb, vb,
                                           Wq, Wk, Wv, Wo, Wqt, Wkt, Wvt, Wot);
    proj_gemm_k<<<dim3(768), 256, 0, stream>>>(
        qb, kb, vb, Wqt, Wkt, Wvt, bq, bk, bv, Qh, Kh, Vt);
    attn_mfma_k<<<dim3(512), 512, 0, stream>>>(Qh, Kh, Vt, An);
    out_gemm_k<<<dim3(512), 256, 0, stream>>>(An, Wot, bo, (float*)d_out);
}